// Round 3
// baseline (1348.638 us; speedup 1.0000x reference)
//
#include <hip/hip_runtime.h>

typedef unsigned short u16;
typedef short bf16x8 __attribute__((ext_vector_type(8)));
typedef float f32x4 __attribute__((ext_vector_type(4)));

__device__ __forceinline__ float bf2f(unsigned v) { return __uint_as_float(v << 16); }
__device__ __forceinline__ u16 f2bf(float f) {
    unsigned u = __float_as_uint(f);
    return (u16)((u + 0x7fffu + ((u >> 16) & 1u)) >> 16);
}

// ---- async global->LDS, width 16B per lane, dest = wave base + lane*16 ----
__device__ __forceinline__ void gload_lds16(const void* g, void* l) {
    __builtin_amdgcn_global_load_lds(
        (const __attribute__((address_space(1))) unsigned int*)g,
        (__attribute__((address_space(3))) unsigned int*)l, 16, 0, 0);
}

// LDS tile swizzle (both-sides): 64B rows of 4x16B granules; granule ^= (row>>1)&3.
// Stage side: global source granule = (lane&3) ^ ((lane>>3)&3)  (row = lane>>2).
// Read side:  granule = quad ^ ((c>>1)&3)                       (row = base16 + c).

// =====================================================================
// Bitmask: bit j of word w  <=>  adj[w*32 + j] > 0   (adj fp32)
__global__ __launch_bounds__(256) void k_mask(const float* __restrict__ adj,
                                              unsigned* __restrict__ mask) {
    int w = blockIdx.x * 256 + threadIdx.x;           // 524288 words
    const float4* q = (const float4*)(adj + (size_t)w * 32);
    unsigned bits = 0u;
#pragma unroll
    for (int i = 0; i < 8; i++) {
        float4 v = q[i];
        if (v.x > 0.f) bits |= (1u << (i * 4 + 0));
        if (v.y > 0.f) bits |= (1u << (i * 4 + 1));
        if (v.z > 0.f) bits |= (1u << (i * 4 + 2));
        if (v.w > 0.f) bits |= (1u << (i * 4 + 3));
    }
    mask[w] = bits;
}

// =====================================================================
// Transpose [K,128] fp32 -> [128,K] bf16 per matrix (batch = blockIdx.z)
__global__ void k_trans(const float* __restrict__ in, u16* __restrict__ out, int K) {
    __shared__ float t[32][33];
    const float* src = in + (size_t)blockIdx.z * K * 128;
    u16* dst = out + (size_t)blockIdx.z * K * 128;
    int k0 = blockIdx.x * 32, n0 = blockIdx.y * 32;
    int tx = threadIdx.x, ty = threadIdx.y;           // 32 x 8
#pragma unroll
    for (int i = 0; i < 32; i += 8) t[ty + i][tx] = src[(size_t)(k0 + ty + i) * 128 + n0 + tx];
    __syncthreads();
#pragma unroll
    for (int i = 0; i < 32; i += 8) dst[(size_t)(n0 + ty + i) * K + k0 + tx] = f2bf(t[tx][ty + i]);
}

// =====================================================================
// fp32 -> bf16 elementwise (entity embedding), 4 elems/thread
__global__ __launch_bounds__(256) void k_cvt(const float* __restrict__ in,
                                             u16* __restrict__ out) {
    int t = blockIdx.x * 256 + threadIdx.x;
    float4 v = ((const float4*)in)[t];
    uint2 o;
    o.x = (unsigned)f2bf(v.x) | ((unsigned)f2bf(v.y) << 16);
    o.y = (unsigned)f2bf(v.z) | ((unsigned)f2bf(v.w) << 16);
    ((uint2*)out)[t] = o;
}

// =====================================================================
// Projection: Wh = x @ W_h  (M=4096, N=128, K=Fin). X bf16, WT bf16 [n][k],
// avec fp32. Writes WhT[n][j] bf16, f1 fp32, and E12 = {2^f2', 2^0.2f2'}
// (f2' = f2*log2e) for the attention kernel's factored softmax.
__global__ __launch_bounds__(1024, 4) void k_proj(const u16* __restrict__ X,
                                                  const u16* __restrict__ WT,
                                                  const float* __restrict__ avec,
                                                  u16* __restrict__ WhT,
                                                  float* __restrict__ f1,
                                                  float* __restrict__ E12g, int Fin) {
    __shared__ u16 As[2][64 * 32];    // 8 KB  [row][k] (swizzled granules)
    __shared__ u16 Bs[2][128 * 32];   // 16 KB [n][k]   (swizzled granules)
    __shared__ float fpart[4][64][2]; // per-colgroup f1/f2 partials
    const int tid = threadIdx.x;
    const int wv = tid >> 6, lane = tid & 63;
    const int rg = wv & 3, cg = wv >> 2;
    const int c = lane & 15, quad = lane >> 4;
    const int bofs = (quad ^ ((c >> 1) & 3)) * 8;     // swizzled read granule
    const int h = blockIdx.y;
    const int j0 = blockIdx.x * 64;
    const u16* Wp = WT + (size_t)h * 128 * Fin;
    const int sgr = ((lane & 3) ^ ((lane >> 3) & 3)) * 8;  // swizzled source granule

#define PROJ_STAGE(buf, kb)                                                              \
    do {                                                                                 \
        if (cg == 0)                                                                     \
            gload_lds16(X + (size_t)(j0 + rg * 16 + (lane >> 2)) * Fin + (kb) + sgr,     \
                        (void*)&As[buf][rg * 16 * 32]);                                  \
        else if (cg <= 2)                                                                \
            gload_lds16(Wp + (size_t)((cg - 1) * 64 + rg * 16 + (lane >> 2)) * Fin + (kb) + sgr, \
                        (void*)&Bs[buf][((cg - 1) * 64 + rg * 16) * 32]);                \
    } while (0)

    PROJ_STAGE(0, 0);
    __syncthreads();

    f32x4 acc[2];
    acc[0] = (f32x4){0.f, 0.f, 0.f, 0.f};
    acc[1] = (f32x4){0.f, 0.f, 0.f, 0.f};

    int it = 0;
    for (int kb = 0; kb < Fin; kb += 32, it++) {
        const int cur = it & 1;
        if (kb + 32 < Fin) PROJ_STAGE(cur ^ 1, kb + 32);
        bf16x8 av = *(const bf16x8*)&As[cur][(rg * 16 + c) * 32 + bofs];
#pragma unroll
        for (int e = 0; e < 2; e++) {
            bf16x8 bv = *(const bf16x8*)&Bs[cur][((cg * 2 + e) * 16 + c) * 32 + bofs];
            acc[e] = __builtin_amdgcn_mfma_f32_16x16x32_bf16(av, bv, acc[e], 0, 0, 0);
        }
        __syncthreads();
    }

    // epilogue: C row = rg*16+quad*4+r, col n = (cg*2+e)*16+c
    u16* Wo = WhT + (size_t)h * 128 * 4096;
    const float* ah = avec + h * 256;
    float p1[4] = {0, 0, 0, 0}, p2[4] = {0, 0, 0, 0};
#pragma unroll
    for (int e = 0; e < 2; e++) {
        const int n = (cg * 2 + e) * 16 + c;
        float a1 = ah[n];
        float a2 = ah[128 + n];
        u16 w4[4];
#pragma unroll
        for (int r = 0; r < 4; r++) {
            float v = acc[e][r];
            w4[r] = f2bf(v);
            p1[r] += v * a1;
            p2[r] += v * a2;
        }
        uint2 pk;
        pk.x = (unsigned)w4[0] | ((unsigned)w4[1] << 16);
        pk.y = (unsigned)w4[2] | ((unsigned)w4[3] << 16);
        *(uint2*)&Wo[(size_t)n * 4096 + j0 + rg * 16 + quad * 4] = pk;
    }
#pragma unroll
    for (int off = 1; off < 16; off <<= 1) {
#pragma unroll
        for (int r = 0; r < 4; r++) {
            p1[r] += __shfl_xor(p1[r], off);
            p2[r] += __shfl_xor(p2[r], off);
        }
    }
    if (c == 0) {
#pragma unroll
        for (int r = 0; r < 4; r++) {
            fpart[cg][rg * 16 + quad * 4 + r][0] = p1[r];
            fpart[cg][rg * 16 + quad * 4 + r][1] = p2[r];
        }
    }
    __syncthreads();
    if (tid < 64) {
        float s1 = fpart[0][tid][0] + fpart[1][tid][0] + fpart[2][tid][0] + fpart[3][tid][0];
        float s2 = fpart[0][tid][1] + fpart[1][tid][1] + fpart[2][tid][1] + fpart[3][tid][1];
        f1[h * 4096 + j0 + tid] = s1;
        const float LOG2E = 1.4426950408889634f;
        float d = s2 * LOG2E;
        float* e12 = E12g + h * 8192 + 2 * (j0 + tid);
        e12[0] = __builtin_amdgcn_exp2f(d);
        e12[1] = __builtin_amdgcn_exp2f(0.2f * d);
    }
}

// =====================================================================
// Fused masked softmax attention + ELU.
// 512 thr = 8 waves; block = 32 i-rows x 4096 j. Each wave owns a PRIVATE
// 512-j chunk (jg = wave id) and BOTH 16-row A-fragments:
//  - every staged Bs tile is read by exactly ONE wave feeding 2 MFMAs
//    (LDS read bytes = staged bytes; 4x less than the r0 structure)
//  - LDS = 66 KB (single-buffer Bs, reused as reduce buffer) -> 2 blocks/CU;
//    the co-resident block's compute covers this block's stage latency.
//  - no exp2 in the k-loop: P = (cond ? C1_i : C2_i) * (cond ? E1_j : E2_j),
//    E1/E2 precomputed by k_proj (global, L2-hot), masks from global bytes.
// 16 k-iters of 32 j per wave; 2x unrolled ping-pong (P computed in the
// stage window between barriers).
template <bool F32OUT>
__global__ __launch_bounds__(512, 4) void k_attn(const u16* __restrict__ WhT,
                                                 const float* __restrict__ f1g,
                                                 const float* __restrict__ E12g,
                                                 const unsigned char* __restrict__ maskb,
                                                 void* __restrict__ outp, int ostride) {
    __shared__ u16 Bs[8][128 * 32];        // 64 KB; reused as red[] after k-loop
    __shared__ float lpart[8][32];         // per-jg row denominators

    const int tid = threadIdx.x;
    const int jg = tid >> 6, lane = tid & 63;
    const int c = lane & 15, quad = lane >> 4;
    const int bofs = (quad ^ ((c >> 1) & 3)) * 8;          // swizzled read granule
    const int sgr = ((lane & 3) ^ ((lane >> 3) & 3)) * 8;  // swizzled source granule
    const int h = blockIdx.y;
    const int i0 = blockIdx.x * 32;
    const float LOG2E = 1.4426950408889634f;
    const u16* Wp = WhT + (size_t)h * 128 * 4096;
    const float* Ep = E12g + h * 8192;

    // wave stages its own [128 n][32 j] tile: 8 gloads of 1KB (16 n-rows each)
#define ATTN_STAGE(kb)                                                                   \
    do {                                                                                 \
        const int jb_ = jg * 512 + (kb) * 32;                                            \
        _Pragma("unroll")                                                                \
        for (int e_ = 0; e_ < 8; e_++)                                                   \
            gload_lds16(Wp + (size_t)(e_ * 16 + (lane >> 2)) * 4096 + jb_ + sgr,         \
                        (void*)&Bs[jg][(e_ * 16) * 32]);                                 \
    } while (0)

    ATTN_STAGE(0);

    // per-row constants (rows c and c+16 of this block's 32-row tile)
    const float rf1a = f1g[h * 4096 + i0 + c] * LOG2E;
    const float rf1b = f1g[h * 4096 + i0 + 16 + c] * LOG2E;
    const float rma = fmaxf(rf1a, 0.2f * rf1a);
    const float rmb = fmaxf(rf1b, 0.2f * rf1b);
    const float C1a = __builtin_amdgcn_exp2f(rf1a - rma);
    const float C2a = __builtin_amdgcn_exp2f(0.2f * rf1a - rma);
    const float Ta  = __builtin_amdgcn_exp2f(-rf1a);
    const float C1b = __builtin_amdgcn_exp2f(rf1b - rmb);
    const float C2b = __builtin_amdgcn_exp2f(0.2f * rf1b - rmb);
    const float Tb  = __builtin_amdgcn_exp2f(-rf1b);

    // mask byte pointers (global, L2-hot); one byte per (row, 8j), index 4*kb
    const unsigned char* mpa = maskb + (size_t)(i0 + c) * 512 + jg * 64 + quad;
    const unsigned char* mpb = maskb + (size_t)(i0 + 16 + c) * 512 + jg * 64 + quad;
    unsigned mA0 = mpa[0], mB0 = mpb[0];   // kb = 0
    unsigned mA1 = mpa[4], mB1 = mpb[4];   // kb = 1

    f32x4 acc0[8], acc1[8];
#pragma unroll
    for (int i = 0; i < 8; i++) {
        acc0[i] = (f32x4){0.f, 0.f, 0.f, 0.f};
        acc1[i] = (f32x4){0.f, 0.f, 0.f, 0.f};
    }
    float lsa = 0.f, lsb = 0.f;

    union AF { bf16x8 v; unsigned u[4]; };
    AF af0a, af0b, af1a, af1b;

#define COMP_P(dstA, dstB, kb, mba_, mbb_)                                               \
    do {                                                                                 \
        const float* ep_ = Ep + 2 * (jg * 512 + (kb) * 32 + quad * 8);                   \
        _Pragma("unroll")                                                                \
        for (int t = 0; t < 8; t += 2) {                                                 \
            float4 e_ = *(const float4*)(ep_ + 2 * t);                                   \
            float pa0 = ((e_.x > Ta) ? C1a : C2a) * ((e_.x > Ta) ? e_.x : e_.y);         \
            float pa1 = ((e_.z > Ta) ? C1a : C2a) * ((e_.z > Ta) ? e_.z : e_.w);         \
            float pb0 = ((e_.x > Tb) ? C1b : C2b) * ((e_.x > Tb) ? e_.x : e_.y);         \
            float pb1 = ((e_.z > Tb) ? C1b : C2b) * ((e_.z > Tb) ? e_.z : e_.w);         \
            unsigned ua0 = ((mba_ >> t) & 1u)       ? (__float_as_uint(pa0) & 0xffff0000u) : 0u; \
            unsigned ua1 = ((mba_ >> (t + 1)) & 1u) ? (__float_as_uint(pa1) & 0xffff0000u) : 0u; \
            unsigned ub0 = ((mbb_ >> t) & 1u)       ? (__float_as_uint(pb0) & 0xffff0000u) : 0u; \
            unsigned ub1 = ((mbb_ >> (t + 1)) & 1u) ? (__float_as_uint(pb1) & 0xffff0000u) : 0u; \
            lsa += __uint_as_float(ua0) + __uint_as_float(ua1);                          \
            lsb += __uint_as_float(ub0) + __uint_as_float(ub1);                          \
            dstA.u[t >> 1] = (ua0 >> 16) | ua1;                                          \
            dstB.u[t >> 1] = (ub0 >> 16) | ub1;                                          \
        }                                                                                \
    } while (0)

#define DO_MFMA(srcA, srcB)                                                              \
    do {                                                                                 \
        _Pragma("unroll")                                                                \
        for (int nt = 0; nt < 8; nt++) {                                                 \
            bf16x8 bv_ = *(const bf16x8*)&Bs[jg][(nt * 16 + c) * 32 + bofs];             \
            acc0[nt] = __builtin_amdgcn_mfma_f32_16x16x32_bf16(srcA.v, bv_, acc0[nt], 0, 0, 0); \
            acc1[nt] = __builtin_amdgcn_mfma_f32_16x16x32_bf16(srcB.v, bv_, acc1[nt], 0, 0, 0); \
        }                                                                                \
    } while (0)

    COMP_P(af0a, af0b, 0, mA0, mB0);
    __syncthreads();                       // drain stage(0)

    for (int kb = 0; kb < 16; kb += 2) {
        DO_MFMA(af0a, af0b);               // tile kb
        __syncthreads();                   // all reads of Bs(kb) done
        ATTN_STAGE(kb + 1);                // overwrite Bs
        if (kb + 2 < 16) { mA0 = mpa[4 * (kb + 2)]; mB0 = mpb[4 * (kb + 2)]; }
        COMP_P(af1a, af1b, kb + 1, mA1, mB1);   // VALU fills the stage window
        __syncthreads();                   // drain stage(kb+1)
        DO_MFMA(af1a, af1b);               // tile kb+1
        __syncthreads();
        if (kb + 2 < 16) {
            ATTN_STAGE(kb + 2);
            mA1 = mpa[4 * (kb + 3)]; mB1 = mpb[4 * (kb + 3)];
            COMP_P(af0a, af0b, kb + 2, mA0, mB0);
        }
        __syncthreads();
    }

    // per-jg row denominators: sum the 4 quads (lanes c, c+16, c+32, c+48)
    lsa += __shfl_xor(lsa, 16);
    lsa += __shfl_xor(lsa, 32);
    lsb += __shfl_xor(lsb, 16);
    lsb += __shfl_xor(lsb, 32);
    if (quad == 0) {
        lpart[jg][c] = lsa;
        lpart[jg][c + 16] = lsb;
    }

    // reduce acc across the 8 jg-waves into red[i][n] (reuses Bs memory)
    float* red = (float*)&Bs[0][0];        // 32*132*4 = 16.9 KB < 64 KB
#pragma unroll
    for (int g = 0; g < 8; g++) {
        __syncthreads();
        if (jg == g) {
#pragma unroll
            for (int f = 0; f < 2; f++) {
#pragma unroll
                for (int nt = 0; nt < 8; nt++) {
#pragma unroll
                    for (int r = 0; r < 4; r++) {
                        int idx = (f * 16 + quad * 4 + r) * 132 + nt * 16 + c;
                        float v = (f == 0) ? acc0[nt][r] : acc1[nt][r];
                        if (g == 0) red[idx] = v;
                        else        red[idx] += v;
                    }
                }
            }
        }
    }
    __syncthreads();

    // epilogue: thread -> (row = tid>>4 in [0,32), col-octet = tid&15)
    const int row = tid >> 4, cb = tid & 15;
    float l = lpart[0][row];
#pragma unroll
    for (int g = 1; g < 8; g++) l += lpart[g][row];
    const float linv = 1.0f / l;
    float vv[8];
#pragma unroll
    for (int t = 0; t < 8; t++) {
        float v = red[row * 132 + cb * 8 + t] * linv;
        vv[t] = v > 0.f ? v : __expf(v) - 1.f;       // ELU
    }
    const size_t obase = (size_t)(i0 + row) * ostride + h * 128 + cb * 8;
    if (F32OUT) {
        float* op = (float*)outp + obase;
        *(float4*)op = *(float4*)&vv[0];
        *(float4*)(op + 4) = *(float4*)&vv[4];
    } else {
        uint4 o;
        o.x = (unsigned)f2bf(vv[0]) | ((unsigned)f2bf(vv[1]) << 16);
        o.y = (unsigned)f2bf(vv[2]) | ((unsigned)f2bf(vv[3]) << 16);
        o.z = (unsigned)f2bf(vv[4]) | ((unsigned)f2bf(vv[5]) << 16);
        o.w = (unsigned)f2bf(vv[6]) | ((unsigned)f2bf(vv[7]) << 16);
        *(uint4*)((u16*)outp + obase) = o;
    }
}

// =====================================================================
// head_relation_combined = entity_emb[head] + relation_emb[relation] (fp32)
__global__ __launch_bounds__(256) void k_gather(const int* __restrict__ head,
                                                const int* __restrict__ rel,
                                                const float* __restrict__ ent,
                                                const float* __restrict__ rele,
                                                float* __restrict__ out) {
    int t = blockIdx.x * 256 + threadIdx.x;   // 131072 threads: row*32 + seg
    int row = t >> 5, sg = t & 31;
    int hh = head[row], rr = rel[row];
    float4 a = ((const float4*)(ent + (size_t)hh * 128))[sg];
    float4 b = ((const float4*)(rele + (size_t)rr * 128))[sg];
    float4 o;
    o.x = a.x + b.x; o.y = a.y + b.y; o.z = a.z + b.z; o.w = a.w + b.w;
    ((float4*)(out + (size_t)row * 128))[sg] = o;
}

// =====================================================================
extern "C" void kernel_launch(void* const* d_in, const int* in_sizes, int n_in,
                              void* d_out, int out_size, void* d_ws, size_t ws_size,
                              hipStream_t stream) {
    const int*   head = (const int*)d_in[0];
    const int*   rel  = (const int*)d_in[1];
    const float* adj  = (const float*)d_in[2];
    const float* ent  = (const float*)d_in[3];
    const float* rele = (const float*)d_in[4];
    const float* W0   = (const float*)d_in[5];
    const float* a0   = (const float*)d_in[6];
    const float* Wm   = (const float*)d_in[7];
    const float* am   = (const float*)d_in[8];
    const float* Wo   = (const float*)d_in[9];
    const float* ao   = (const float*)d_in[10];

    char* ws = (char*)d_ws;
    unsigned* mask = (unsigned*)(ws + 0);                 // 2 MB
    u16* WT0 = (u16*)(ws + 2097152);                      // 128 KB
    u16* WT5 = (u16*)(ws + 2228224);                      // 37 * 128 KB = 4.625 MB
    u16* WhT = (u16*)(ws + 7077888);                      // 4 MB
    float* f1 = (float*)(ws + 11272192);                  // 64 KB
    u16* xA = (u16*)(ws + 11403264);                      // 4 MB
    u16* xB = (u16*)(ws + 15597568);                      // 4 MB
    u16* x0 = (u16*)(ws + 19791872);                      // 1 MB
    float* E12 = (float*)(ws + 20840448);                 // 128 KB (total 20 MiB)

    float* out_x = (float*)d_out;
    float* out_comb = out_x + (size_t)4096 * 128;

    k_mask<<<2048, 256, 0, stream>>>(adj, mask);
    k_cvt<<<512, 256, 0, stream>>>(ent, x0);
    k_trans<<<dim3(4, 4, 4), dim3(32, 8), 0, stream>>>(W0, WT0, 128);
    k_trans<<<dim3(16, 4, 36), dim3(32, 8), 0, stream>>>(Wm, WT5, 512);
    k_trans<<<dim3(16, 4, 1), dim3(32, 8), 0, stream>>>(Wo, WT5 + (size_t)36 * 512 * 128, 512);
    k_gather<<<512, 256, 0, stream>>>(head, rel, ent, rele, out_comb);

    // layer 0 : D -> H*D
    k_proj<<<dim3(64, 4), 1024, 0, stream>>>(x0, WT0, a0, WhT, f1, E12, 128);
    k_attn<false><<<dim3(128, 4), 512, 0, stream>>>(WhT, f1, E12, (const unsigned char*)mask, xA, 512);
    u16 *xc = xA, *xn = xB;
    // 9 middle layers : H*D -> H*D
    for (int l = 0; l < 9; l++) {
        k_proj<<<dim3(64, 4), 1024, 0, stream>>>(xc, WT5 + (size_t)l * 4 * 512 * 128,
                                                 am + (size_t)l * 4 * 256, WhT, f1, E12, 512);
        k_attn<false><<<dim3(128, 4), 512, 0, stream>>>(WhT, f1, E12, (const unsigned char*)mask, xn, 512);
        u16* t = xc; xc = xn; xn = t;
    }
    // output layer : H*D -> D, single head, fp32 out
    k_proj<<<dim3(64, 1), 1024, 0, stream>>>(xc, WT5 + (size_t)36 * 512 * 128, ao, WhT, f1, E12, 512);
    k_attn<true><<<dim3(128, 1), 512, 0, stream>>>(WhT, f1, E12, (const unsigned char*)mask, out_x, 128);
}

// Round 4
// 748.378 us; speedup vs baseline: 1.8021x; 1.8021x over previous
//
#include <hip/hip_runtime.h>

typedef unsigned short u16;
typedef short bf16x8 __attribute__((ext_vector_type(8)));
typedef float f32x4 __attribute__((ext_vector_type(4)));

__device__ __forceinline__ float bf2f(unsigned v) { return __uint_as_float(v << 16); }
__device__ __forceinline__ u16 f2bf(float f) {
    unsigned u = __float_as_uint(f);
    return (u16)((u + 0x7fffu + ((u >> 16) & 1u)) >> 16);
}

// ---- async global->LDS, width 16B per lane, dest = wave base + lane*16 ----
__device__ __forceinline__ void gload_lds16(const void* g, void* l) {
    __builtin_amdgcn_global_load_lds(
        (const __attribute__((address_space(1))) unsigned int*)g,
        (__attribute__((address_space(3))) unsigned int*)l, 16, 0, 0);
}

// LDS tile swizzle (both-sides): 64B rows of 4x16B granules; granule ^= (row>>1)&3.
// Stage side: global source granule = (lane&3) ^ ((lane>>3)&3)  (row = lane>>2).
// Read side:  granule = quad ^ ((c>>1)&3)                       (row = base16 + c).

// =====================================================================
// Bitmask: bit j of word w  <=>  adj[w*32 + j] > 0   (adj fp32)
__global__ __launch_bounds__(256) void k_mask(const float* __restrict__ adj,
                                              unsigned* __restrict__ mask) {
    int w = blockIdx.x * 256 + threadIdx.x;           // 524288 words
    const float4* q = (const float4*)(adj + (size_t)w * 32);
    unsigned bits = 0u;
#pragma unroll
    for (int i = 0; i < 8; i++) {
        float4 v = q[i];
        if (v.x > 0.f) bits |= (1u << (i * 4 + 0));
        if (v.y > 0.f) bits |= (1u << (i * 4 + 1));
        if (v.z > 0.f) bits |= (1u << (i * 4 + 2));
        if (v.w > 0.f) bits |= (1u << (i * 4 + 3));
    }
    mask[w] = bits;
}

// =====================================================================
// Transpose [K,128] fp32 -> [128,K] bf16 per matrix (batch = blockIdx.z)
__global__ void k_trans(const float* __restrict__ in, u16* __restrict__ out, int K) {
    __shared__ float t[32][33];
    const float* src = in + (size_t)blockIdx.z * K * 128;
    u16* dst = out + (size_t)blockIdx.z * K * 128;
    int k0 = blockIdx.x * 32, n0 = blockIdx.y * 32;
    int tx = threadIdx.x, ty = threadIdx.y;           // 32 x 8
#pragma unroll
    for (int i = 0; i < 32; i += 8) t[ty + i][tx] = src[(size_t)(k0 + ty + i) * 128 + n0 + tx];
    __syncthreads();
#pragma unroll
    for (int i = 0; i < 32; i += 8) dst[(size_t)(n0 + ty + i) * K + k0 + tx] = f2bf(t[tx][ty + i]);
}

// =====================================================================
// fp32 -> bf16 elementwise (entity embedding), 4 elems/thread
__global__ __launch_bounds__(256) void k_cvt(const float* __restrict__ in,
                                             u16* __restrict__ out) {
    int t = blockIdx.x * 256 + threadIdx.x;
    float4 v = ((const float4*)in)[t];
    uint2 o;
    o.x = (unsigned)f2bf(v.x) | ((unsigned)f2bf(v.y) << 16);
    o.y = (unsigned)f2bf(v.z) | ((unsigned)f2bf(v.w) << 16);
    ((uint2*)out)[t] = o;
}

// =====================================================================
// Projection: Wh = x @ W_h  (M=4096, N=128, K=Fin). X bf16, WT bf16 [n][k],
// avec fp32. Writes WhT[n][j] bf16, f1 fp32, and E12 = {2^f2', 2^0.2f2'}
// (f2' = f2*log2e) for the attention kernel's factored softmax.
__global__ __launch_bounds__(1024, 4) void k_proj(const u16* __restrict__ X,
                                                  const u16* __restrict__ WT,
                                                  const float* __restrict__ avec,
                                                  u16* __restrict__ WhT,
                                                  float* __restrict__ f1,
                                                  float* __restrict__ E12g, int Fin) {
    __shared__ u16 As[2][64 * 32];    // 8 KB  [row][k] (swizzled granules)
    __shared__ u16 Bs[2][128 * 32];   // 16 KB [n][k]   (swizzled granules)
    __shared__ float fpart[4][64][2]; // per-colgroup f1/f2 partials
    const int tid = threadIdx.x;
    const int wv = tid >> 6, lane = tid & 63;
    const int rg = wv & 3, cg = wv >> 2;
    const int c = lane & 15, quad = lane >> 4;
    const int bofs = (quad ^ ((c >> 1) & 3)) * 8;     // swizzled read granule
    const int h = blockIdx.y;
    const int j0 = blockIdx.x * 64;
    const u16* Wp = WT + (size_t)h * 128 * Fin;
    const int sgr = ((lane & 3) ^ ((lane >> 3) & 3)) * 8;  // swizzled source granule

#define PROJ_STAGE(buf, kb)                                                              \
    do {                                                                                 \
        if (cg == 0)                                                                     \
            gload_lds16(X + (size_t)(j0 + rg * 16 + (lane >> 2)) * Fin + (kb) + sgr,     \
                        (void*)&As[buf][rg * 16 * 32]);                                  \
        else if (cg <= 2)                                                                \
            gload_lds16(Wp + (size_t)((cg - 1) * 64 + rg * 16 + (lane >> 2)) * Fin + (kb) + sgr, \
                        (void*)&Bs[buf][((cg - 1) * 64 + rg * 16) * 32]);                \
    } while (0)

    PROJ_STAGE(0, 0);
    __syncthreads();

    f32x4 acc[2];
    acc[0] = (f32x4){0.f, 0.f, 0.f, 0.f};
    acc[1] = (f32x4){0.f, 0.f, 0.f, 0.f};

    int it = 0;
    for (int kb = 0; kb < Fin; kb += 32, it++) {
        const int cur = it & 1;
        if (kb + 32 < Fin) PROJ_STAGE(cur ^ 1, kb + 32);
        bf16x8 av = *(const bf16x8*)&As[cur][(rg * 16 + c) * 32 + bofs];
#pragma unroll
        for (int e = 0; e < 2; e++) {
            bf16x8 bv = *(const bf16x8*)&Bs[cur][((cg * 2 + e) * 16 + c) * 32 + bofs];
            acc[e] = __builtin_amdgcn_mfma_f32_16x16x32_bf16(av, bv, acc[e], 0, 0, 0);
        }
        __syncthreads();
    }

    // epilogue: C row = rg*16+quad*4+r, col n = (cg*2+e)*16+c
    u16* Wo = WhT + (size_t)h * 128 * 4096;
    const float* ah = avec + h * 256;
    float p1[4] = {0, 0, 0, 0}, p2[4] = {0, 0, 0, 0};
#pragma unroll
    for (int e = 0; e < 2; e++) {
        const int n = (cg * 2 + e) * 16 + c;
        float a1 = ah[n];
        float a2 = ah[128 + n];
        u16 w4[4];
#pragma unroll
        for (int r = 0; r < 4; r++) {
            float v = acc[e][r];
            w4[r] = f2bf(v);
            p1[r] += v * a1;
            p2[r] += v * a2;
        }
        uint2 pk;
        pk.x = (unsigned)w4[0] | ((unsigned)w4[1] << 16);
        pk.y = (unsigned)w4[2] | ((unsigned)w4[3] << 16);
        *(uint2*)&Wo[(size_t)n * 4096 + j0 + rg * 16 + quad * 4] = pk;
    }
#pragma unroll
    for (int off = 1; off < 16; off <<= 1) {
#pragma unroll
        for (int r = 0; r < 4; r++) {
            p1[r] += __shfl_xor(p1[r], off);
            p2[r] += __shfl_xor(p2[r], off);
        }
    }
    if (c == 0) {
#pragma unroll
        for (int r = 0; r < 4; r++) {
            fpart[cg][rg * 16 + quad * 4 + r][0] = p1[r];
            fpart[cg][rg * 16 + quad * 4 + r][1] = p2[r];
        }
    }
    __syncthreads();
    if (tid < 64) {
        float s1 = fpart[0][tid][0] + fpart[1][tid][0] + fpart[2][tid][0] + fpart[3][tid][0];
        float s2 = fpart[0][tid][1] + fpart[1][tid][1] + fpart[2][tid][1] + fpart[3][tid][1];
        f1[h * 4096 + j0 + tid] = s1;
        const float LOG2E = 1.4426950408889634f;
        float d = s2 * LOG2E;
        float* e12 = E12g + h * 8192 + 2 * (j0 + tid);
        e12[0] = __builtin_amdgcn_exp2f(d);
        e12[1] = __builtin_amdgcn_exp2f(0.2f * d);
    }
}

// =====================================================================
// Fused masked softmax attention + ELU — r0 structure (the 42.7 us one):
// 1024 thr = 16 waves = 4 row-groups x 4 j-groups (1024 j each), one
// 16-row A-fragment per wave, double-buffered Bs, ONE barrier per k-iter.
// Changes vs r0 (each individually proven in rounds 1-3 passing builds):
//  - Bs XOR-swizzle (conflicts 4.4M -> ~0)
//  - factored softmax: P = (cond ? C1_i : C2_i)*(cond ? E1_j : E2_j);
//    E1/E2 precomputed by k_proj, loaded from GLOBAL (L2, wave-broadcast
//    addresses) with ping-pong register prefetch -> no exp2/fmax/fma in
//    the inner loop, f2s LDS reads gone
//  - row denominators via ones-MFMA (exact over the same truncated bf16 P)
//  - red[] aliased onto Bs after the k-loop; LDS 151 -> 98 KB
template <bool F32OUT>
__global__ __launch_bounds__(1024, 4) void k_attn(const u16* __restrict__ WhT,
                                                  const float* __restrict__ f1g,
                                                  const float* __restrict__ E12g,
                                                  const unsigned char* __restrict__ maskb,
                                                  void* __restrict__ outp, int ostride) {
    __shared__ unsigned char ms[64 * 528]; // 33 KB padded mask rows
    __shared__ u16 Bs[2][4][128 * 32];     // 64 KB double-buffered WhT tiles
    __shared__ float lpart[4][64];         // per-jgroup row denominators

    const int tid = threadIdx.x;
    const int wv = tid >> 6, lane = tid & 63;
    const int jg = wv >> 2, rg = wv & 3;
    const int c = lane & 15, quad = lane >> 4;
    const int bofs = (quad ^ ((c >> 1) & 3)) * 8;          // swizzled read granule
    const int sgr = ((lane & 3) ^ ((lane >> 3) & 3)) * 8;  // swizzled source granule
    const int h = blockIdx.y;
    const int i0 = blockIdx.x * 64;
    const float LOG2E = 1.4426950408889634f;
    const u16* Wp = WhT + (size_t)h * 128 * 4096;

#define ATTN_STAGE(buf, kb)                                                              \
    do {                                                                                 \
        const int jb_ = jg * 1024 + (kb) * 32;                                           \
        _Pragma("unroll")                                                                \
        for (int e_ = 0; e_ < 2; e_++)                                                   \
            gload_lds16(Wp + (size_t)(rg * 32 + e_ * 16 + (lane >> 2)) * 4096 + jb_ + sgr, \
                        (void*)&Bs[buf][jg][(rg * 32 + e_ * 16) * 32]);                  \
    } while (0)

    // ---- prologue: stage mask rows, stage tile 0 ----
    {   // 64 rows x 512 B of mask = 2048 uint4
        const uint4* msrc = (const uint4*)(maskb + (size_t)i0 * 512);
#pragma unroll
        for (int e = 0; e < 2; e++) {
            int o = tid + e * 1024;
            uint4 v = msrc[o];
            int row = o >> 5, col = o & 31;
            *(uint4*)&ms[row * 528 + col * 16] = v;
        }
    }
    ATTN_STAGE(0, 0);

    // per-i constants (one fragment row per thread, as r0)
    const int iloc = rg * 16 + c;
    const float rf1 = f1g[h * 4096 + i0 + iloc] * LOG2E;
    const float rm = fmaxf(rf1, 0.2f * rf1);
    const float C1 = __builtin_amdgcn_exp2f(rf1 - rm);
    const float C2 = __builtin_amdgcn_exp2f(0.2f * rf1 - rm);
    const float T  = __builtin_amdgcn_exp2f(-rf1);

    // E12 global pointer: wave-uniform across c (broadcast loads from L2)
    const float* ep = E12g + h * 8192 + jg * 2048 + quad * 16;
    float4 eA[4], eB[4];
#pragma unroll
    for (int q = 0; q < 4; q++) eA[q] = *(const float4*)(ep + 0 * 64 + q * 4);
#pragma unroll
    for (int q = 0; q < 4; q++) eB[q] = *(const float4*)(ep + 1 * 64 + q * 4);

    bf16x8 onesv;
#pragma unroll
    for (int i = 0; i < 8; i++) onesv[i] = (short)0x3F80;

    f32x4 acc[8];
#pragma unroll
    for (int i = 0; i < 8; i++) acc[i] = (f32x4){0.f, 0.f, 0.f, 0.f};
    f32x4 acc_l = (f32x4){0.f, 0.f, 0.f, 0.f};

    union AF { bf16x8 v; unsigned u[4]; };
    AF afA, afB;

#define COMP_P(dst, mb_, E_)                                                             \
    do {                                                                                 \
        _Pragma("unroll")                                                                \
        for (int t = 0; t < 8; t += 2) {                                                 \
            float4 e_ = E_[t >> 1];                                                      \
            float p0 = ((e_.x > T) ? C1 : C2) * ((e_.x > T) ? e_.x : e_.y);              \
            float p1 = ((e_.z > T) ? C1 : C2) * ((e_.z > T) ? e_.z : e_.w);              \
            unsigned u0 = ((mb_ >> t) & 1u)       ? (__float_as_uint(p0) & 0xffff0000u) : 0u; \
            unsigned u1 = ((mb_ >> (t + 1)) & 1u) ? (__float_as_uint(p1) & 0xffff0000u) : 0u; \
            dst.u[t >> 1] = (u0 >> 16) | u1;                                             \
        }                                                                                \
    } while (0)

#define DO_MFMA(src, buf)                                                                \
    do {                                                                                 \
        _Pragma("unroll")                                                                \
        for (int nt = 0; nt < 8; nt++) {                                                 \
            bf16x8 bv_ = *(const bf16x8*)&Bs[buf][jg][(nt * 16 + c) * 32 + bofs];        \
            acc[nt] = __builtin_amdgcn_mfma_f32_16x16x32_bf16(src.v, bv_, acc[nt], 0, 0, 0); \
        }                                                                                \
        acc_l = __builtin_amdgcn_mfma_f32_16x16x32_bf16(src.v, onesv, acc_l, 0, 0, 0);   \
    } while (0)

    const unsigned char* mrow = &ms[iloc * 528 + jg * 128 + quad];
    __syncthreads();                       // ms visible; tile-0 staging drained

    for (int kb = 0; kb < 32; kb += 2) {
        // ---- body A: tile kb (buf0); prefetch kb+1 stage, kb+2 E-vals ----
        ATTN_STAGE(1, kb + 1);
        {
            const unsigned mbA = mrow[kb * 4];
            COMP_P(afA, mbA, eA);
        }
        if (kb + 2 < 32) {
#pragma unroll
            for (int q = 0; q < 4; q++) eA[q] = *(const float4*)(ep + (kb + 2) * 64 + q * 4);
        }
        DO_MFMA(afA, 0);
        __syncthreads();
        // ---- body B: tile kb+1 (buf1); prefetch kb+2 stage, kb+3 E-vals ----
        if (kb + 2 < 32) ATTN_STAGE(0, kb + 2);
        {
            const unsigned mbB = mrow[(kb + 1) * 4];
            COMP_P(afB, mbB, eB);
        }
        if (kb + 3 < 32) {
#pragma unroll
            for (int q = 0; q < 4; q++) eB[q] = *(const float4*)(ep + (kb + 3) * 64 + q * 4);
        }
        DO_MFMA(afB, 1);
        __syncthreads();
    }

    // row denominators straight from the ones-MFMA accumulator
    if (c == 0) {
#pragma unroll
        for (int r = 0; r < 4; r++)
            lpart[jg][rg * 16 + quad * 4 + r] = acc_l[r];
    }

    // reduce acc across j-groups into red[i][n] (aliases dead Bs memory)
    float* red = (float*)&Bs[0][0][0];     // 64*132*4 = 33.8 KB < 64 KB
#pragma unroll
    for (int g = 0; g < 4; g++) {
        __syncthreads();
        if (jg == g) {
#pragma unroll
            for (int nt = 0; nt < 8; nt++) {
#pragma unroll
                for (int r = 0; r < 4; r++) {
                    int idx = (rg * 16 + quad * 4 + r) * 132 + nt * 16 + c;
                    if (g == 0) red[idx] = acc[nt][r];
                    else        red[idx] += acc[nt][r];
                }
            }
        }
    }
    __syncthreads();

    // epilogue: thread -> (row = tid>>4, col-octet = tid&15)
    const int row = tid >> 4, cb = tid & 15;
    const float l = lpart[0][row] + lpart[1][row] + lpart[2][row] + lpart[3][row];
    const float linv = 1.0f / l;
    float vv[8];
#pragma unroll
    for (int t = 0; t < 8; t++) {
        float v = red[row * 132 + cb * 8 + t] * linv;
        vv[t] = v > 0.f ? v : __expf(v) - 1.f;       // ELU
    }
    const size_t obase = (size_t)(i0 + row) * ostride + h * 128 + cb * 8;
    if (F32OUT) {
        float* op = (float*)outp + obase;
        *(float4*)op = *(float4*)&vv[0];
        *(float4*)(op + 4) = *(float4*)&vv[4];
    } else {
        uint4 o;
        o.x = (unsigned)f2bf(vv[0]) | ((unsigned)f2bf(vv[1]) << 16);
        o.y = (unsigned)f2bf(vv[2]) | ((unsigned)f2bf(vv[3]) << 16);
        o.z = (unsigned)f2bf(vv[4]) | ((unsigned)f2bf(vv[5]) << 16);
        o.w = (unsigned)f2bf(vv[6]) | ((unsigned)f2bf(vv[7]) << 16);
        *(uint4*)((u16*)outp + obase) = o;
    }
}

// =====================================================================
// head_relation_combined = entity_emb[head] + relation_emb[relation] (fp32)
__global__ __launch_bounds__(256) void k_gather(const int* __restrict__ head,
                                                const int* __restrict__ rel,
                                                const float* __restrict__ ent,
                                                const float* __restrict__ rele,
                                                float* __restrict__ out) {
    int t = blockIdx.x * 256 + threadIdx.x;   // 131072 threads: row*32 + seg
    int row = t >> 5, sg = t & 31;
    int hh = head[row], rr = rel[row];
    float4 a = ((const float4*)(ent + (size_t)hh * 128))[sg];
    float4 b = ((const float4*)(rele + (size_t)rr * 128))[sg];
    float4 o;
    o.x = a.x + b.x; o.y = a.y + b.y; o.z = a.z + b.z; o.w = a.w + b.w;
    ((float4*)(out + (size_t)row * 128))[sg] = o;
}

// =====================================================================
extern "C" void kernel_launch(void* const* d_in, const int* in_sizes, int n_in,
                              void* d_out, int out_size, void* d_ws, size_t ws_size,
                              hipStream_t stream) {
    const int*   head = (const int*)d_in[0];
    const int*   rel  = (const int*)d_in[1];
    const float* adj  = (const float*)d_in[2];
    const float* ent  = (const float*)d_in[3];
    const float* rele = (const float*)d_in[4];
    const float* W0   = (const float*)d_in[5];
    const float* a0   = (const float*)d_in[6];
    const float* Wm   = (const float*)d_in[7];
    const float* am   = (const float*)d_in[8];
    const float* Wo   = (const float*)d_in[9];
    const float* ao   = (const float*)d_in[10];

    char* ws = (char*)d_ws;
    unsigned* mask = (unsigned*)(ws + 0);                 // 2 MB
    u16* WT0 = (u16*)(ws + 2097152);                      // 128 KB
    u16* WT5 = (u16*)(ws + 2228224);                      // 37 * 128 KB = 4.625 MB
    u16* WhT = (u16*)(ws + 7077888);                      // 4 MB
    float* f1 = (float*)(ws + 11272192);                  // 64 KB
    u16* xA = (u16*)(ws + 11403264);                      // 4 MB
    u16* xB = (u16*)(ws + 15597568);                      // 4 MB
    u16* x0 = (u16*)(ws + 19791872);                      // 1 MB
    float* E12 = (float*)(ws + 20840448);                 // 128 KB (total ~21 MB)

    float* out_x = (float*)d_out;
    float* out_comb = out_x + (size_t)4096 * 128;

    k_mask<<<2048, 256, 0, stream>>>(adj, mask);
    k_cvt<<<512, 256, 0, stream>>>(ent, x0);
    k_trans<<<dim3(4, 4, 4), dim3(32, 8), 0, stream>>>(W0, WT0, 128);
    k_trans<<<dim3(16, 4, 36), dim3(32, 8), 0, stream>>>(Wm, WT5, 512);
    k_trans<<<dim3(16, 4, 1), dim3(32, 8), 0, stream>>>(Wo, WT5 + (size_t)36 * 512 * 128, 512);
    k_gather<<<512, 256, 0, stream>>>(head, rel, ent, rele, out_comb);

    // layer 0 : D -> H*D
    k_proj<<<dim3(64, 4), 1024, 0, stream>>>(x0, WT0, a0, WhT, f1, E12, 128);
    k_attn<false><<<dim3(64, 4), 1024, 0, stream>>>(WhT, f1, E12, (const unsigned char*)mask, xA, 512);
    u16 *xc = xA, *xn = xB;
    // 9 middle layers : H*D -> H*D
    for (int l = 0; l < 9; l++) {
        k_proj<<<dim3(64, 4), 1024, 0, stream>>>(xc, WT5 + (size_t)l * 4 * 512 * 128,
                                                 am + (size_t)l * 4 * 256, WhT, f1, E12, 512);
        k_attn<false><<<dim3(64, 4), 1024, 0, stream>>>(WhT, f1, E12, (const unsigned char*)mask, xn, 512);
        u16* t = xc; xc = xn; xn = t;
    }
    // output layer : H*D -> D, single head, fp32 out
    k_proj<<<dim3(64, 1), 1024, 0, stream>>>(xc, WT5 + (size_t)36 * 512 * 128, ao, WhT, f1, E12, 512);
    k_attn<true><<<dim3(64, 1), 1024, 0, stream>>>(WhT, f1, E12, (const unsigned char*)mask, out_x, 128);
}